// Round 11
// baseline (243.731 us; speedup 1.0000x reference)
//
#include <hip/hip_runtime.h>
#include <hip/hip_bf16.h>

// QKVAttention: L2-distance attention. B=8, T=4096, C=192, fp32 in/out.
// out[b,t,:] = sum_s exp(-||q_t-k_s||*192^-0.5) v_s / sum_s exp(...)
// exp arg bounded in [-3,0] -> no online softmax needed.
//
// R15 = R14 + two latency/VALU trims. R14 post-mortem: VALUBusy -4pts with
// ZERO time delta -> per-score VALU off the critical path; corrected cycle
// model (16x16x32 MFMA ~19 cyc/SIMD) shows matrix 32%, VALU 34%, DS ~52%,
// wall = per-iter dependency chain, not a pipe. Changes:
//  1. attn2: S-accumulate split into two 3-deep MFMA chains per sacc
//     (+8 v_add_f32): cuts ~100 cyc of exposed dependent-MFMA latency/iter.
//     FP reassociation only (margin 2.4e-4 << 1.08e-3).
//  2. prep: conversion loop uses v_cvt_pk_bf16_f32 (36 inst) instead of
//     manual RNE f2bf x72 (216 VALU) — same rounding, proven in R14 P-path.
//     (prep est. 45-50us of the 86us non-attn2 residual; never in top-5.)

#define BB 8
#define TT 4096
#define CD 192

typedef __attribute__((ext_vector_type(8))) short short8;   // 8 bf16 (4 VGPR)
typedef __attribute__((ext_vector_type(4))) float float4v;  // MFMA C/D
typedef __attribute__((ext_vector_type(4))) unsigned uint4v;
typedef __attribute__((ext_vector_type(2))) unsigned int uint2v;

// (log2 e)^2 / 192  : p = exp2(-sqrt(max(q2A+k2A-2*A2C*dot, 0)))
constexpr float A2C = (float)(2.0813689810056077 / 192.0);

static __device__ __forceinline__ unsigned short f2bf(float f) {
  unsigned u = __builtin_bit_cast(unsigned, f);
  unsigned r = u + 0x7fffu + ((u >> 16) & 1u);   // RNE (inputs finite)
  return (unsigned short)(r >> 16);
}
static __device__ __forceinline__ float bf2f(unsigned short b) {
  return __builtin_bit_cast(float, (unsigned)b << 16);
}
static __device__ __forceinline__ unsigned cvtpk_bf16(float lo, float hi) {
  unsigned r;                  // D[15:0]=bf16(lo), D[31:16]=bf16(hi), RNE
  asm("v_cvt_pk_bf16_f32 %0, %1, %2" : "=v"(r) : "v"(lo), "v"(hi));
  return r;
}

// ---------------- fused prepass: qkv -> qsw/ksw/vsw fragments + q2/k2 -------
// block = (b, sc): 32 tokens x 576 ch. Coalesced float4 read -> bf16 LDS tile,
// then emit MFMA-fragment units (64 lanes x 16B each) + A2C-prescaled rounded
// row sumsq. No atomics: each block owns its 32 tokens' q2/k2 entries.
__global__ __launch_bounds__(256) void prep(
    const float* __restrict__ qkv, short8* __restrict__ qsw,
    short8* __restrict__ ksw, short8* __restrict__ vsw,
    float* __restrict__ q2, float* __restrict__ k2) {
  __shared__ unsigned short tile[32 * 584];   // row stride 584 (1168B, 16-mult)
  const int t = threadIdx.x;
  const int b = blockIdx.x >> 7;
  const int sc = blockIdx.x & 127;
  const float* src = qkv + ((size_t)(b * TT + sc * 32)) * (3 * CD);
#pragma unroll
  for (int j = 0; j < 18; ++j) {              // 4608 float4s / 256 thr
    int f = j * 256 + t;
    int row = f / 144, c4 = (f % 144) * 4;
    float4v x = *(const float4v*)(src + (size_t)row * 576 + c4);
    unsigned r0 = cvtpk_bf16(x[0], x[1]);     // HW RNE pack (was 3-op manual)
    unsigned r1 = cvtpk_bf16(x[2], x[3]);
    *(uint2v*)&tile[row * 584 + c4] = (uint2v){r0, r1};
  }
  __syncthreads();

  const int lane = t & 63, w = t >> 6;
  const int L = lane & 15, q = lane >> 4;
  // waves 0,1 -> q (s16o = w), waves 2,3 -> k (s16o = w-2)
  const int which = w >> 1;
  const int s16o = w & 1;
  const int row = s16o * 16 + L;
  short8* dst = which ? ksw : qsw;
  const size_t ubase = ((size_t)(b * 256 + sc * 2 + s16o)) * 6;
  float ss = 0.f;
#pragma unroll
  for (int ch = 0; ch < 6; ++ch) {
    short8 fr = *(const short8*)&tile[row * 584 + which * CD + ch * 32 + q * 8];
#pragma unroll
    for (int j = 0; j < 8; ++j) {
      float f = bf2f((unsigned short)fr[j]);
      ss += f * f;
    }
    dst[(ubase + ch) * 64 + lane] = fr;
  }
  ss += __shfl_xor(ss, 16);
  ss += __shfl_xor(ss, 32);                   // sum over 4 quads (192 ch)
  if (lane < 16)
    (which ? k2 : q2)[b * TT + sc * 32 + s16o * 16 + lane] = ss * A2C;

  // v fragments: 12 nt2-units, 3 per wave. lane(q,L): V[q*8+j][nt2*16+L]
#pragma unroll
  for (int i = 0; i < 3; ++i) {
    int nt2 = w * 3 + i;
    short8 fr;
#pragma unroll
    for (int j = 0; j < 8; ++j)
      fr[j] = (short)tile[(q * 8 + j) * 584 + 2 * CD + nt2 * 16 + L];
    vsw[((size_t)(b * 12 + nt2) * 128 + sc) * 64 + lane] = fr;
  }
}

// ---------------- main fused attention --------------------------------------
// grid 512 = 8 b x 64 q-tiles; block 256 = 4 waves x 16 q-rows.
// 128 s-iters of 32; K,V LDS double-buffered via global_load_lds width 16.
// 58368B LDS -> 2 blocks/CU (independent barriers overlap each other's drain).
__global__ __launch_bounds__(256, 2) void attn2(
    const short8* __restrict__ qsw, const short8* __restrict__ ksw,
    const short8* __restrict__ vsw, const float* __restrict__ q2,
    const float* __restrict__ k2, float* __restrict__ out) {
  // LDS: K dbuf 2x12KB | V dbuf 2x12KB | P scratch 4 waves x 16x36 fp32
  __shared__ __align__(16) unsigned char s_lds[49152 + 9216];
  float* ldsP = (float*)(s_lds + 49152);

  const int tid = threadIdx.x;
  const int w = tid >> 6;
  const int lane = tid & 63;
  const int L = lane & 15;
  const int q = lane >> 4;
  const int b = blockIdx.x & 7;      // batch -> XCD (and blk, blk+256 same CU
  const int qt = blockIdx.x >> 3;    //   share batch -> shared K/V in L2)
  const int q0 = qt * 64 + w * 16;   // this wave's 16 q-rows
  const size_t bT = (size_t)b * TT;

  float* pw = ldsP + w * 576;        // wave-private 16x36 P scratch

  // staging pointers (strength-reduced: += const stride per tile)
  const char* gka[3];
  const char* gva[3];
  char* lka[3];
  char* lva[3];
#pragma unroll
  for (int j = 0; j < 3; ++j) {
    int u = w * 3 + j;
    gka[j] = (const char*)ksw + ((size_t)(b * 256) * 6 * 64 + u * 64 + lane) * 16;
    gva[j] = (const char*)vsw + (((size_t)(b * 12 + u) * 128) * 64 + lane) * 16;
    lka[j] = (char*)s_lds + u * 1024;
    lva[j] = (char*)s_lds + 24576 + u * 1024;
  }
  // issue stage of current tile into buf, advance pointers to next tile
  auto stage = [&](int buf) {
#pragma unroll
    for (int j = 0; j < 3; ++j) {
      __builtin_amdgcn_global_load_lds(
          (const __attribute__((address_space(1))) void*)gka[j],
          (__attribute__((address_space(3))) void*)(lka[j] + buf * 12288), 16, 0, 0);
      gka[j] += 12288;             // 2 s16-units x 6 ch x 64 lanes x 16B
    }
#pragma unroll
    for (int j = 0; j < 3; ++j) {
      __builtin_amdgcn_global_load_lds(
          (const __attribute__((address_space(1))) void*)gva[j],
          (__attribute__((address_space(3))) void*)(lva[j] + buf * 12288), 16, 0, 0);
      gva[j] += 1024;              // 64 lanes x 16B per itile
    }
  };

  // Q fragments: unit ((b*256 + s16)*6 + ch), s16 = q0/16 = qt*4 + w
  short8 qf[6];
#pragma unroll
  for (int ch = 0; ch < 6; ++ch)
    qf[ch] = qsw[((size_t)(b * 256 + (q0 >> 4)) * 6 + ch) * 64 + lane];

  float q2l[4];
#pragma unroll
  for (int r = 0; r < 4; ++r) q2l[r] = q2[bT + q0 + 4 * q + r];

  float4v oacc[12];
#pragma unroll
  for (int nt = 0; nt < 12; ++nt) oacc[nt] = (float4v){0.f, 0.f, 0.f, 0.f};
  float lsum[4] = {0.f, 0.f, 0.f, 0.f};

  stage(0);
  // k2 for tile 0 (prefetched each iter thereafter)
  float k2l[2];
  k2l[0] = k2[bT + L];
  k2l[1] = k2[bT + 16 + L];
  __syncthreads();   // drains vmcnt -> tile0 ready

#pragma unroll 1
  for (int it = 0; it < 128; ++it) {
    const int cur = it & 1;
    if (it + 1 < 128) stage(cur ^ 1);   // overlap with compute

    // prefetch next tile's k2 (used next iter; hides scalar-load latency)
    float k2n[2];
    if (it + 1 < 128) {
      k2n[0] = k2[bT + (it + 1) * 32 + L];
      k2n[1] = k2[bT + (it + 1) * 32 + 16 + L];
    }

    // ---- S = Q.K^T: two 3-deep chains per accumulator (latency split) ----
    float4v s0a = (float4v){0.f, 0.f, 0.f, 0.f};
    float4v s0b = (float4v){0.f, 0.f, 0.f, 0.f};
    float4v s1a = (float4v){0.f, 0.f, 0.f, 0.f};
    float4v s1b = (float4v){0.f, 0.f, 0.f, 0.f};
#pragma unroll
    for (int ch = 0; ch < 6; ch += 2) {
      short8 kf0 = *(const short8*)(s_lds + cur * 12288 + ch * 1024 + lane * 16);
      short8 kf1 = *(const short8*)(s_lds + cur * 12288 + (6 + ch) * 1024 + lane * 16);
      short8 kf0b = *(const short8*)(s_lds + cur * 12288 + (ch + 1) * 1024 + lane * 16);
      short8 kf1b = *(const short8*)(s_lds + cur * 12288 + (7 + ch) * 1024 + lane * 16);
      s0a = __builtin_amdgcn_mfma_f32_16x16x32_bf16(qf[ch], kf0, s0a, 0, 0, 0);
      s1a = __builtin_amdgcn_mfma_f32_16x16x32_bf16(qf[ch], kf1, s1a, 0, 0, 0);
      s0b = __builtin_amdgcn_mfma_f32_16x16x32_bf16(qf[ch + 1], kf0b, s0b, 0, 0, 0);
      s1b = __builtin_amdgcn_mfma_f32_16x16x32_bf16(qf[ch + 1], kf1b, s1b, 0, 0, 0);
    }
    float4v sacc[2];
    sacc[0] = s0a + s0b;
    sacc[1] = s1a + s1b;

    // ---- V fragments from LDS (issue early; used after P) ----
    short8 vf[12];
#pragma unroll
    for (int nt = 0; nt < 12; ++nt)
      vf[nt] = *(const short8*)(s_lds + 24576 + cur * 12288 + nt * 1024 + lane * 16);

    // ---- P = exp(-dist); C-layout row=4q+r, col=nt*16+L -> LDS -> A-layout --
#pragma unroll
    for (int nt = 0; nt < 2; ++nt)
#pragma unroll
      for (int r = 0; r < 4; ++r) {
        float dot = sacc[nt][r];
        float tt = fmaf(-2.f * A2C, dot, q2l[r] + k2l[nt]);   // scaled d2
        float y = fmaxf(tt, 0.f);
        float p = __builtin_amdgcn_exp2f(-__builtin_amdgcn_sqrtf(y));
        lsum[r] += p;
        pw[(4 * q + r) * 36 + nt * 16 + L] = p;
      }
    float4v p0 = *(const float4v*)(pw + L * 36 + q * 8);
    float4v p1 = *(const float4v*)(pw + L * 36 + q * 8 + 4);
    // pack 8 fp32 -> 8 bf16 with 4 HW cvt_pk (RNE)
    uint4v pd;
    pd[0] = cvtpk_bf16(p0[0], p0[1]);
    pd[1] = cvtpk_bf16(p0[2], p0[3]);
    pd[2] = cvtpk_bf16(p1[0], p1[1]);
    pd[3] = cvtpk_bf16(p1[2], p1[3]);
    short8 paf = __builtin_bit_cast(short8, pd);

    // ---- O += P.V ----
#pragma unroll
    for (int nt = 0; nt < 12; ++nt)
      oacc[nt] = __builtin_amdgcn_mfma_f32_16x16x32_bf16(paf, vf[nt], oacc[nt], 0, 0, 0);

    k2l[0] = k2n[0];
    k2l[1] = k2n[1];
    __syncthreads();   // drain stage(it+1) + release buf[cur]
  }

  // ---- epilogue: normalize, write out (wave-private) ----
#pragma unroll
  for (int r = 0; r < 4; ++r) {
    float ls = lsum[r];
#pragma unroll
    for (int m = 1; m < 16; m <<= 1) ls += __shfl_xor(ls, m);
    float linv = 1.f / ls;
#pragma unroll
    for (int nt = 0; nt < 12; ++nt)
      out[(bT + q0 + 4 * q + r) * CD + nt * 16 + L] = oacc[nt][r] * linv;
  }
}

extern "C" void kernel_launch(void* const* d_in, const int* in_sizes, int n_in,
                              void* d_out, int out_size, void* d_ws, size_t ws_size,
                              hipStream_t stream) {
  (void)in_sizes; (void)n_in; (void)out_size; (void)ws_size;
  const float* qkv = (const float*)d_in[0];
  float* out = (float*)d_out;

  short8* qsw = (short8*)d_ws;                       // 8*256*6 units
  short8* ksw = qsw + (size_t)BB * 256 * 6 * 64;
  short8* vsw = ksw + (size_t)BB * 256 * 6 * 64;     // 8*12*128 units
  float* q2 = (float*)(vsw + (size_t)BB * 12 * 128 * 64);
  float* k2 = q2 + (size_t)BB * TT;

  prep<<<BB * 128, 256, 0, stream>>>(qkv, qsw, ksw, vsw, q2, k2);
  attn2<<<BB * 64, 256, 0, stream>>>(qsw, ksw, vsw, q2, k2, out);
}